// Round 1
// baseline (10999.773 us; speedup 1.0000x reference)
//
#include <hip/hip_runtime.h>

#define Bsz 256
#define Tt  128
#define EMB 256
#define HID 512
#define VOC 1004
#define FCI 2048

// Generic C[m,n] = sum_k A[m,k]*Bw[n,k] (+bias[n]) (+C0[m/c0div, n])
// 64x64 tile, K-step 16, 256 threads, 4x4 micro-tile.
__global__ __launch_bounds__(256)
void gemm_bt(const float* __restrict__ A, const float* __restrict__ Bw,
             const float* __restrict__ bias, const float* __restrict__ C0,
             float* __restrict__ C,
             int M, int N, int K, int lda, int ldb, int ldc, int ldc0, int c0div)
{
    __shared__ float As[16][68];
    __shared__ float Bs[16][68];
    const int n0 = blockIdx.x * 64;
    const int m0 = blockIdx.y * 64;
    const int tid = threadIdx.x;
    const int tx = tid & 15, ty = tid >> 4;
    float acc[4][4];
#pragma unroll
    for (int i = 0; i < 4; i++)
#pragma unroll
        for (int j = 0; j < 4; j++) acc[i][j] = 0.f;

    for (int k0 = 0; k0 < K; k0 += 16) {
#pragma unroll
        for (int i = 0; i < 4; i++) {
            int e = tid + i * 256;
            int m = e >> 4, k = e & 15;
            As[k][m] = A[(size_t)(m0 + m) * lda + (k0 + k)];   // M always %64==0 here
        }
#pragma unroll
        for (int i = 0; i < 4; i++) {
            int e = tid + i * 256;
            int n = e >> 4, k = e & 15;
            int gn = n0 + n;
            Bs[k][n] = (gn < N) ? Bw[(size_t)gn * ldb + (k0 + k)] : 0.f;
        }
        __syncthreads();
#pragma unroll
        for (int kk = 0; kk < 16; kk++) {
            float4 av = *(const float4*)&As[kk][ty * 4];
            float4 bv = *(const float4*)&Bs[kk][tx * 4];
            float a[4] = {av.x, av.y, av.z, av.w};
            float b[4] = {bv.x, bv.y, bv.z, bv.w};
#pragma unroll
            for (int i = 0; i < 4; i++)
#pragma unroll
                for (int j = 0; j < 4; j++)
                    acc[i][j] += a[i] * b[j];
        }
        __syncthreads();
    }
#pragma unroll
    for (int i = 0; i < 4; i++) {
        int m = m0 + ty * 4 + i;
        const float* c0row = C0 ? (C0 + (size_t)(m / c0div) * ldc0) : nullptr;
#pragma unroll
        for (int j = 0; j < 4; j++) {
            int n = n0 + tx * 4 + j;
            if (n < N) {
                float v = acc[i][j];
                if (bias)  v += bias[n];
                if (c0row) v += c0row[n];
                C[(size_t)m * ldc + n] = v;
            }
        }
    }
}

// One LSTM timestep: gates[b,n] = gin[b,t,n] + h_in @ Whh^T, then cell update.
// Block owns 32 b x 32 j (all 4 gate chunks for those j) -> c is block-local.
__global__ __launch_bounds__(256)
void lstm_step(const float* __restrict__ gin, const float* __restrict__ Whh,
               const float* __restrict__ h_in, float* __restrict__ h_out,
               float* __restrict__ cst, float* __restrict__ hiddens, int t)
{
    __shared__ float Hs[32][33];
    __shared__ float Ws[4][32][33];
    const int j0 = blockIdx.x * 32;
    const int b0 = blockIdx.y * 32;
    const int tid = threadIdx.x;
    const int tx = tid & 31, ty = tid >> 5;   // tx: j within tile, ty: b group
    float acc[4][4];                           // [r (b)], [q (gate chunk)]
#pragma unroll
    for (int r = 0; r < 4; r++)
#pragma unroll
        for (int q = 0; q < 4; q++) acc[r][q] = 0.f;

    for (int k0 = 0; k0 < HID; k0 += 32) {
#pragma unroll
        for (int i = 0; i < 4; i++) {
            int e = tid + i * 256;
            int bb = e >> 5, kk = e & 31;
            Hs[bb][kk] = h_in[(b0 + bb) * HID + k0 + kk];
        }
#pragma unroll
        for (int i = 0; i < 16; i++) {
            int e = tid + i * 256;          // < 4096
            int q = e >> 10, rem = e & 1023;
            int jj = rem >> 5, kk = rem & 31;
            Ws[q][jj][kk] = Whh[(size_t)(q * HID + j0 + jj) * HID + k0 + kk];
        }
        __syncthreads();
#pragma unroll
        for (int kk = 0; kk < 32; kk++) {
            float w0 = Ws[0][tx][kk], w1 = Ws[1][tx][kk];
            float w2 = Ws[2][tx][kk], w3 = Ws[3][tx][kk];
#pragma unroll
            for (int r = 0; r < 4; r++) {
                float hv = Hs[ty + 8 * r][kk];
                acc[r][0] += hv * w0;
                acc[r][1] += hv * w1;
                acc[r][2] += hv * w2;
                acc[r][3] += hv * w3;
            }
        }
        __syncthreads();
    }

    const int j = j0 + tx;
#pragma unroll
    for (int r = 0; r < 4; r++) {
        int b = b0 + ty + 8 * r;
        const float* g = gin + (size_t)(b * Tt + t) * (4 * HID);
        float iv = acc[r][0] + g[j];
        float fv = acc[r][1] + g[HID + j];
        float gv = acc[r][2] + g[2 * HID + j];
        float ov = acc[r][3] + g[3 * HID + j];
        float si = 1.f / (1.f + __expf(-iv));
        float sf = 1.f / (1.f + __expf(-fv));
        float so = 1.f / (1.f + __expf(-ov));
        float tg = 1.f - 2.f / (1.f + __expf(2.f * gv));     // tanh(g)
        float cv = sf * cst[b * HID + j] + si * tg;
        cst[b * HID + j] = cv;
        float th = 1.f - 2.f / (1.f + __expf(2.f * cv));     // tanh(c)
        float hv = so * th;
        h_out[b * HID + j] = hv;
        hiddens[(size_t)(b * Tt + t) * HID + j] = hv;
    }
}

extern "C" void kernel_launch(void* const* d_in, const int* in_sizes, int n_in,
                              void* d_out, int out_size, void* d_ws, size_t ws_size,
                              hipStream_t stream)
{
    const float* images = (const float*)d_in[0];
    const float* caps   = (const float*)d_in[1];
    const float* W_fc   = (const float*)d_in[2];
    const float* b_fc   = (const float*)d_in[3];
    const float* W_att  = (const float*)d_in[4];
    const float* b_att  = (const float*)d_in[5];
    const float* W_ih   = (const float*)d_in[6];
    const float* b_ih   = (const float*)d_in[7];
    const float* W_hh   = (const float*)d_in[8];
    const float* b_hh   = (const float*)d_in[9];
    const float* W_out  = (const float*)d_in[10];
    const float* b_out  = (const float*)d_in[11];
    float* out = (float*)d_out;

    float* ws       = (float*)d_ws;
    float* feats    = ws;                  // 256*256
    float* att_base = feats + 65536;       // 256*256
    float* gin_base = att_base + 65536;    // 256*2048
    float* hA       = gin_base + 524288;   // 256*512
    float* hB       = hA + 131072;
    float* cst      = hB + 131072;
    float* ctx_all  = cst + 131072;        // 32768*256
    float* hiddens  = ctx_all + 8388608;   // 32768*512
    float* gin_all  = hiddens + 16777216;  // 32768*2048

    // 1. feats = images @ W_fc^T + b_fc            [256,256]
    gemm_bt<<<dim3(4, 4), 256, 0, stream>>>(images, W_fc, b_fc, nullptr, feats,
        256, 256, 2048, 2048, 2048, 256, 0, 1);
    // 2. att_base = feats @ W_att[:, :256]^T + b_att   [256,256]
    gemm_bt<<<dim3(4, 4), 256, 0, stream>>>(feats, W_att, b_att, nullptr, att_base,
        256, 256, 256, 256, 768, 256, 0, 1);
    // 3. gin_base = feats @ W_ih[:, :256]^T + b_ih     [256,2048]
    gemm_bt<<<dim3(32, 4), 256, 0, stream>>>(feats, W_ih, b_ih, nullptr, gin_base,
        256, 2048, 256, 256, 512, 2048, 0, 1);
    // 4. ctx_all = caps @ W_att[:, 256:]^T + att_base  [32768,256]
    gemm_bt<<<dim3(4, 512), 256, 0, stream>>>(caps, W_att + 256, nullptr, att_base, ctx_all,
        32768, 256, 512, 512, 768, 256, 256, Tt);
    // 5. gin_all = ctx_all @ W_ih[:, 256:]^T + gin_base + b_hh   [32768,2048]
    gemm_bt<<<dim3(32, 512), 256, 0, stream>>>(ctx_all, W_ih + 256, b_hh, gin_base, gin_all,
        32768, 2048, 256, 256, 512, 2048, 2048, Tt);
    // 6. recurrence
    hipMemsetAsync(hA, 0, 131072 * sizeof(float), stream);
    hipMemsetAsync(cst, 0, 131072 * sizeof(float), stream);
    for (int t = 0; t < Tt; t++) {
        const float* hi = (t & 1) ? hB : hA;
        float* ho = (t & 1) ? hA : hB;
        lstm_step<<<dim3(16, 8), 256, 0, stream>>>(gin_all, W_hh, hi, ho, cst, hiddens, t);
    }
    // 7. out = hiddens @ W_out^T + b_out   [32768,1004]
    gemm_bt<<<dim3(16, 512), 256, 0, stream>>>(hiddens, W_out, b_out, nullptr, out,
        32768, 1004, 512, 512, 512, 1004, 0, 1);
}

// Round 2
// 8629.771 us; speedup vs baseline: 1.2746x; 1.2746x over previous
//
#include <hip/hip_runtime.h>
#include <hip/hip_cooperative_groups.h>

namespace cg = cooperative_groups;

#define Tt  128
#define HID 512

// Generic C[m,n] = sum_k A[m,k]*Bw[n,k] (+bias[n]) (+C0[m/c0div, n])
// 64x64 tile, K-step 16, 256 threads, 4x4 micro-tile.
__global__ __launch_bounds__(256)
void gemm_bt(const float* __restrict__ A, const float* __restrict__ Bw,
             const float* __restrict__ bias, const float* __restrict__ C0,
             float* __restrict__ C,
             int M, int N, int K, int lda, int ldb, int ldc, int ldc0, int c0div)
{
    __shared__ float As[16][68];
    __shared__ float Bs[16][68];
    const int n0 = blockIdx.x * 64;
    const int m0 = blockIdx.y * 64;
    const int tid = threadIdx.x;
    const int tx = tid & 15, ty = tid >> 4;
    float acc[4][4];
#pragma unroll
    for (int i = 0; i < 4; i++)
#pragma unroll
        for (int j = 0; j < 4; j++) acc[i][j] = 0.f;

    for (int k0 = 0; k0 < K; k0 += 16) {
#pragma unroll
        for (int i = 0; i < 4; i++) {
            int e = tid + i * 256;
            int m = e >> 4, k = e & 15;
            As[k][m] = A[(size_t)(m0 + m) * lda + (k0 + k)];
        }
#pragma unroll
        for (int i = 0; i < 4; i++) {
            int e = tid + i * 256;
            int n = e >> 4, k = e & 15;
            int gn = n0 + n;
            Bs[k][n] = (gn < N) ? Bw[(size_t)gn * ldb + (k0 + k)] : 0.f;
        }
        __syncthreads();
#pragma unroll
        for (int kk = 0; kk < 16; kk++) {
            float4 av = *(const float4*)&As[kk][ty * 4];
            float4 bv = *(const float4*)&Bs[kk][tx * 4];
            float a[4] = {av.x, av.y, av.z, av.w};
            float b[4] = {bv.x, bv.y, bv.z, bv.w};
#pragma unroll
            for (int i = 0; i < 4; i++)
#pragma unroll
                for (int j = 0; j < 4; j++)
                    acc[i][j] += a[i] * b[j];
        }
        __syncthreads();
    }
#pragma unroll
    for (int i = 0; i < 4; i++) {
        int m = m0 + ty * 4 + i;
        const float* c0row = C0 ? (C0 + (size_t)(m / c0div) * ldc0) : nullptr;
#pragma unroll
        for (int j = 0; j < 4; j++) {
            int n = n0 + tx * 4 + j;
            if (n < N) {
                float v = acc[i][j];
                if (bias)  v += bias[n];
                if (c0row) v += c0row[n];
                C[(size_t)m * ldc + n] = v;
            }
        }
    }
}

// Persistent cooperative LSTM recurrence.
// 256 blocks (1/CU): bt = blockIdx&7 (32 b rows), jt = blockIdx>>3 (16 j cols).
// W_hh slice [4g][16j][512k] resident in LDS (128 KB) for all 128 steps.
// c-state in registers. h double-buffered in global, grid.sync() per step.
// Wave w owns b-octet w*8..w*8+7; lane l owns (j = l>>2, g = l&3).
__global__ __launch_bounds__(256, 1)
void lstm_seq(const float* __restrict__ gin, const float* __restrict__ Whh,
              float* __restrict__ hA, float* __restrict__ hB,
              float* __restrict__ hiddens)
{
    __shared__ float4 Ws4[8192];   // [k4 0..127][j 0..15][g 0..3]  128 KB
    __shared__ float4 Hs4[1024];   // [k4 0..31][b ^ k4]            16 KB (chunk of h)
    float* Gs = (float*)Hs4;       // alias: gates [32b][16j][4g]    8 KB

    const int tid = threadIdx.x;
    const int l   = tid & 63;
    const int w   = tid >> 6;
    const int w8  = w * 8;
    const int bt  = blockIdx.x & 7;    // consecutive blocks -> different bt (XCD-local h heuristic)
    const int jt  = blockIdx.x >> 3;
    const int b0  = bt * 32;
    const int j0  = jt * 16;

    // Load W_hh slice into LDS once: rows g*512 + j0 + j, all 512 k.
    const float4* Whh4 = (const float4*)Whh;
#pragma unroll
    for (int i = 0; i < 32; i++) {
        int e4 = tid + i * 256;            // 8192 float4s
        int k4 = e4 & 127, gj = e4 >> 7;
        int g_ = gj >> 4, j_ = gj & 15;
        Ws4[k4 * 64 + j_ * 4 + g_] = Whh4[(size_t)(g_ * HID + j0 + j_) * 128 + k4];
    }

    float cr[2] = {0.f, 0.f};
    cg::grid_group grid = cg::this_grid();
    __syncthreads();

    for (int t = 0; t < Tt; t++) {
        float acc[8] = {0.f, 0.f, 0.f, 0.f, 0.f, 0.f, 0.f, 0.f};
        if (t > 0) {
            // h_{t-1} lives in buffer (t-1)&1
            const float4* hin4 = (const float4*)(((t - 1) & 1) ? hB : hA);
            for (int c = 0; c < 4; c++) {
                __syncthreads();           // Hs4 reuse from previous chunk / Gs
#pragma unroll
                for (int i = 0; i < 4; i++) {
                    int e4 = tid + i * 256;        // 1024 float4s = 32b x 32kq
                    int bb_ = e4 >> 5, kq = e4 & 31;
                    Hs4[kq * 32 + (bb_ ^ kq)] = hin4[(b0 + bb_) * 128 + c * 32 + kq];
                }
                __syncthreads();
#pragma unroll
                for (int k4 = 0; k4 < 32; k4++) {
                    float4 wv = Ws4[(c * 32 + k4) * 64 + l];
#pragma unroll
                    for (int bb = 0; bb < 8; bb++) {
                        float4 hv = Hs4[k4 * 32 + ((w8 + bb) ^ k4)];   // broadcast read
                        acc[bb] += wv.x * hv.x + wv.y * hv.y + wv.z * hv.z + wv.w * hv.w;
                    }
                }
            }
        }
        __syncthreads();                   // last chunk compute done before Gs overwrite
#pragma unroll
        for (int bb = 0; bb < 8; bb++)
            Gs[(w8 + bb) * 64 + l] = acc[bb];
        __syncthreads();

        // Cell update: thread owns 2 (b,j) pairs, c in registers across steps.
        float* hw = (t & 1) ? hB : hA;
#pragma unroll
        for (int u = 0; u < 2; u++) {
            int p = tid * 2 + u;
            int bl = p >> 4, jj = p & 15;
            int bg = b0 + bl, jg = j0 + jj;
            const float* gp = gin + (size_t)(bg * Tt + t) * 2048 + jg;
            float gi = Gs[bl * 64 + jj * 4 + 0] + gp[0];
            float gf = Gs[bl * 64 + jj * 4 + 1] + gp[HID];
            float gg = Gs[bl * 64 + jj * 4 + 2] + gp[2 * HID];
            float go = Gs[bl * 64 + jj * 4 + 3] + gp[3 * HID];
            float si = 1.f / (1.f + __expf(-gi));
            float sf = 1.f / (1.f + __expf(-gf));
            float so = 1.f / (1.f + __expf(-go));
            float tg = 1.f - 2.f / (1.f + __expf(2.f * gg));
            float cv = sf * cr[u] + si * tg;
            cr[u] = cv;
            float th = 1.f - 2.f / (1.f + __expf(2.f * cv));
            float hv = so * th;
            hw[bg * HID + jg] = hv;
            hiddens[(size_t)(bg * Tt + t) * HID + jg] = hv;
        }
        grid.sync();
    }
}

extern "C" void kernel_launch(void* const* d_in, const int* in_sizes, int n_in,
                              void* d_out, int out_size, void* d_ws, size_t ws_size,
                              hipStream_t stream)
{
    const float* images = (const float*)d_in[0];
    const float* caps   = (const float*)d_in[1];
    const float* W_fc   = (const float*)d_in[2];
    const float* b_fc   = (const float*)d_in[3];
    const float* W_att  = (const float*)d_in[4];
    const float* b_att  = (const float*)d_in[5];
    const float* W_ih   = (const float*)d_in[6];
    const float* b_ih   = (const float*)d_in[7];
    const float* W_hh   = (const float*)d_in[8];
    const float* b_hh   = (const float*)d_in[9];
    const float* W_out  = (const float*)d_in[10];
    const float* b_out  = (const float*)d_in[11];
    float* out = (float*)d_out;

    float* ws       = (float*)d_ws;
    float* feats    = ws;                  // 256*256
    float* att_base = feats + 65536;       // 256*256
    float* gin_base = att_base + 65536;    // 256*2048
    float* hA       = gin_base + 524288;   // 256*512
    float* hB       = hA + 131072;
    float* cst      = hB + 131072;         // unused now
    float* ctx_all  = cst + 131072;        // 32768*256
    float* hiddens  = ctx_all + 8388608;   // 32768*512
    float* gin_all  = hiddens + 16777216;  // 32768*2048

    // 1. feats = images @ W_fc^T + b_fc            [256,256]
    gemm_bt<<<dim3(4, 4), 256, 0, stream>>>(images, W_fc, b_fc, nullptr, feats,
        256, 256, 2048, 2048, 2048, 256, 0, 1);
    // 2. att_base = feats @ W_att[:, :256]^T + b_att   [256,256]
    gemm_bt<<<dim3(4, 4), 256, 0, stream>>>(feats, W_att, b_att, nullptr, att_base,
        256, 256, 256, 256, 768, 256, 0, 1);
    // 3. gin_base = feats @ W_ih[:, :256]^T + b_ih     [256,2048]
    gemm_bt<<<dim3(32, 4), 256, 0, stream>>>(feats, W_ih, b_ih, nullptr, gin_base,
        256, 2048, 256, 256, 512, 2048, 0, 1);
    // 4. ctx_all = caps @ W_att[:, 256:]^T + att_base  [32768,256]
    gemm_bt<<<dim3(4, 512), 256, 0, stream>>>(caps, W_att + 256, nullptr, att_base, ctx_all,
        32768, 256, 512, 512, 768, 256, 256, Tt);
    // 5. gin_all = ctx_all @ W_ih[:, 256:]^T + gin_base + b_hh   [32768,2048]
    gemm_bt<<<dim3(32, 512), 256, 0, stream>>>(ctx_all, W_ih + 256, b_hh, gin_base, gin_all,
        32768, 2048, 256, 256, 512, 2048, 2048, Tt);

    // 6. recurrence: one persistent cooperative kernel, 256 blocks = 1/CU
    {
        void* args[] = { (void*)&gin_all, (void*)&W_hh, (void*)&hA, (void*)&hB,
                         (void*)&hiddens };
        hipLaunchCooperativeKernel((void*)lstm_seq, dim3(256), dim3(256),
                                   args, 0, stream);
    }

    // 7. out = hiddens @ W_out^T + b_out   [32768,1004]
    gemm_bt<<<dim3(16, 512), 256, 0, stream>>>(hiddens, W_out, b_out, nullptr, out,
        32768, 1004, 512, 512, 512, 1004, 0, 1);
}

// Round 3
// 6175.426 us; speedup vs baseline: 1.7812x; 1.3974x over previous
//
#include <hip/hip_runtime.h>

#define Tt  128
#define HID 512

// Generic C[m,n] = sum_k A[m,k]*Bw[n,k] (+bias[n]) (+C0[m/c0div, n])
// 64x64 tile, K-step 16, 256 threads, 4x4 micro-tile.
__global__ __launch_bounds__(256)
void gemm_bt(const float* __restrict__ A, const float* __restrict__ Bw,
             const float* __restrict__ bias, const float* __restrict__ C0,
             float* __restrict__ C,
             int M, int N, int K, int lda, int ldb, int ldc, int ldc0, int c0div)
{
    __shared__ float As[16][68];
    __shared__ float Bs[16][68];
    const int n0 = blockIdx.x * 64;
    const int m0 = blockIdx.y * 64;
    const int tid = threadIdx.x;
    const int tx = tid & 15, ty = tid >> 4;
    float acc[4][4];
#pragma unroll
    for (int i = 0; i < 4; i++)
#pragma unroll
        for (int j = 0; j < 4; j++) acc[i][j] = 0.f;

    for (int k0 = 0; k0 < K; k0 += 16) {
#pragma unroll
        for (int i = 0; i < 4; i++) {
            int e = tid + i * 256;
            int m = e >> 4, k = e & 15;
            As[k][m] = A[(size_t)(m0 + m) * lda + (k0 + k)];
        }
#pragma unroll
        for (int i = 0; i < 4; i++) {
            int e = tid + i * 256;
            int n = e >> 4, k = e & 15;
            int gn = n0 + n;
            Bs[k][n] = (gn < N) ? Bw[(size_t)gn * ldb + (k0 + k)] : 0.f;
        }
        __syncthreads();
#pragma unroll
        for (int kk = 0; kk < 16; kk++) {
            float4 av = *(const float4*)&As[kk][ty * 4];
            float4 bv = *(const float4*)&Bs[kk][tx * 4];
            float a[4] = {av.x, av.y, av.z, av.w};
            float b[4] = {bv.x, bv.y, bv.z, bv.w};
#pragma unroll
            for (int i = 0; i < 4; i++)
#pragma unroll
                for (int j = 0; j < 4; j++)
                    acc[i][j] += a[i] * b[j];
        }
        __syncthreads();
    }
#pragma unroll
    for (int i = 0; i < 4; i++) {
        int m = m0 + ty * 4 + i;
        const float* c0row = C0 ? (C0 + (size_t)(m / c0div) * ldc0) : nullptr;
#pragma unroll
        for (int j = 0; j < 4; j++) {
            int n = n0 + tx * 4 + j;
            if (n < N) {
                float v = acc[i][j];
                if (bias)  v += bias[n];
                if (c0row) v += c0row[n];
                C[(size_t)m * ldc + n] = v;
            }
        }
    }
}

// Persistent LSTM recurrence, 256 blocks x 1024 threads (1 block/CU, 16 waves).
// bt = blockIdx&7 (32 b rows), jt = blockIdx>>3 (16 j cols, all 4 gates).
// W_hh slice resident in LDS (128 KB, XOR-swizzled: pos(row,k4) = k4*64 + (row^(k4&63))).
// Sync: per-bt flag counters (agent-scope release/acquire), NOT grid.sync —
// 8 independent 32-block pipelines. c-state in registers (gl==0 lanes).
// Wave w owns b rows {2w,2w+1}; lane l owns (j = l>>2, gate = l&3).
__global__ __launch_bounds__(1024, 4)
void lstm_seq(const float* __restrict__ gin, const float* __restrict__ Whh,
              float* __restrict__ hA, float* __restrict__ hB,
              float* __restrict__ hiddens, unsigned int* __restrict__ flags)
{
    __shared__ float4 Ws4[8192];   // 128 KB: W slice, swizzled
    __shared__ float4 Hs4[1024];   // 16 KB: [bb 0..31][kq 0..31] chunk of h
    const int tid = threadIdx.x;
    const int l   = tid & 63;
    const int w   = tid >> 6;
    const int bt  = blockIdx.x & 7;
    const int jt  = blockIdx.x >> 3;
    const int b0  = bt * 32;
    const int j0  = jt * 16;
    const int jl  = l >> 2;
    const int gl  = l & 3;

    // One-time W_hh slice load. Lanes run along k4 (coalesced global,
    // conflict-free LDS via XOR swizzle since k4&63 == lane).
    const float4* Whh4 = (const float4*)Whh;
#pragma unroll
    for (int i = 0; i < 8; i++) {
        int row = w + (i & 3) * 16;              // [0,64) = j*4+g
        int k4  = (i >> 2) * 64 + l;             // [0,128)
        int j_ = row >> 2, g_ = row & 3;
        Ws4[k4 * 64 + (row ^ (k4 & 63))] =
            Whh4[(size_t)(g_ * HID + j0 + j_) * 128 + k4];
    }

    float cr[2] = {0.f, 0.f};
    __syncthreads();

    for (int t = 0; t < Tt; t++) {
        // prefetch gin for this thread's (b=2w+u, j=jl, gate=gl) slots
        float gp[2];
#pragma unroll
        for (int u = 0; u < 2; u++) {
            int bg = b0 + w * 2 + u;
            gp[u] = gin[((size_t)bg * Tt + t) * 2048 + gl * HID + j0 + jl];
        }
        float acc0 = 0.f, acc1 = 0.f;
        if (t > 0) {
            if (tid == 0) {
                while (__hip_atomic_load(&flags[bt], __ATOMIC_ACQUIRE,
                                         __HIP_MEMORY_SCOPE_AGENT) < 32u * (unsigned)t)
                    __builtin_amdgcn_s_sleep(1);
            }
            __syncthreads();
            const float4* hin4 = (const float4*)(((t - 1) & 1) ? hB : hA);
            for (int c = 0; c < 4; c++) {
                {
                    int kq = tid & 31, bb = tid >> 5;
                    Hs4[bb * 32 + kq] = hin4[(size_t)(b0 + bb) * 128 + c * 32 + kq];
                }
                __syncthreads();
#pragma unroll
                for (int k4 = 0; k4 < 32; k4++) {
                    int kg = c * 32 + k4;
                    float4 wv = Ws4[kg * 64 + (l ^ (kg & 63))];
                    float4 h0 = Hs4[(w * 2 + 0) * 32 + k4];   // broadcast
                    float4 h1 = Hs4[(w * 2 + 1) * 32 + k4];   // broadcast
                    acc0 += wv.x * h0.x + wv.y * h0.y + wv.z * h0.z + wv.w * h0.w;
                    acc1 += wv.x * h1.x + wv.y * h1.y + wv.z * h1.z + wv.w * h1.w;
                }
                __syncthreads();
            }
        }
        float ga0 = acc0 + gp[0];
        float ga1 = acc1 + gp[1];
        // gather the 4 gate pre-activations into the gl==0 lane of each quad
        int lb = l & ~3;
        float f0 = __shfl(ga0, lb + 1, 64), f1 = __shfl(ga1, lb + 1, 64);
        float g0 = __shfl(ga0, lb + 2, 64), g1 = __shfl(ga1, lb + 2, 64);
        float o0 = __shfl(ga0, lb + 3, 64), o1 = __shfl(ga1, lb + 3, 64);
        float* hw = (t & 1) ? hB : hA;
        if (gl == 0) {
#pragma unroll
            for (int u = 0; u < 2; u++) {
                float gi = u ? ga1 : ga0;
                float gf = u ? f1 : f0;
                float gg = u ? g1 : g0;
                float go = u ? o1 : o0;
                float si = 1.f / (1.f + __expf(-gi));
                float sf = 1.f / (1.f + __expf(-gf));
                float so = 1.f / (1.f + __expf(-go));
                float tg = 1.f - 2.f / (1.f + __expf(2.f * gg));
                float cv = sf * cr[u] + si * tg;
                cr[u] = cv;
                float th = 1.f - 2.f / (1.f + __expf(2.f * cv));
                float hv = so * th;
                int bg = b0 + w * 2 + u, jg = j0 + jl;
                hw[bg * HID + jg] = hv;
                hiddens[((size_t)bg * Tt + t) * HID + jg] = hv;
            }
        }
        __syncthreads();   // all waves drain their h stores (vmcnt0 at barrier)
        if (tid == 0) {
            __threadfence();                      // agent fence: L2 writeback
            __hip_atomic_fetch_add(&flags[bt], 1u, __ATOMIC_RELEASE,
                                   __HIP_MEMORY_SCOPE_AGENT);
        }
    }
}

extern "C" void kernel_launch(void* const* d_in, const int* in_sizes, int n_in,
                              void* d_out, int out_size, void* d_ws, size_t ws_size,
                              hipStream_t stream)
{
    const float* images = (const float*)d_in[0];
    const float* caps   = (const float*)d_in[1];
    const float* W_fc   = (const float*)d_in[2];
    const float* b_fc   = (const float*)d_in[3];
    const float* W_att  = (const float*)d_in[4];
    const float* b_att  = (const float*)d_in[5];
    const float* W_ih   = (const float*)d_in[6];
    const float* b_ih   = (const float*)d_in[7];
    const float* W_hh   = (const float*)d_in[8];
    const float* b_hh   = (const float*)d_in[9];
    const float* W_out  = (const float*)d_in[10];
    const float* b_out  = (const float*)d_in[11];
    float* out = (float*)d_out;

    float* ws       = (float*)d_ws;
    float* feats    = ws;                  // 256*256
    float* att_base = feats + 65536;       // 256*256
    float* gin_base = att_base + 65536;    // 256*2048
    float* hA       = gin_base + 524288;   // 256*512
    float* hB       = hA + 131072;
    float* ctx_all  = hB + 131072;         // 32768*256
    float* hiddens  = ctx_all + 8388608;   // 32768*512
    float* gin_all  = hiddens + 16777216;  // 32768*2048
    unsigned int* flags = (unsigned int*)(gin_all + 67108864);  // 8 counters

    hipMemsetAsync(flags, 0, 8 * sizeof(unsigned int), stream);

    // 1. feats = images @ W_fc^T + b_fc            [256,256]
    gemm_bt<<<dim3(4, 4), 256, 0, stream>>>(images, W_fc, b_fc, nullptr, feats,
        256, 256, 2048, 2048, 2048, 256, 0, 1);
    // 2. att_base = feats @ W_att[:, :256]^T + b_att   [256,256]
    gemm_bt<<<dim3(4, 4), 256, 0, stream>>>(feats, W_att, b_att, nullptr, att_base,
        256, 256, 256, 256, 768, 256, 0, 1);
    // 3. gin_base = feats @ W_ih[:, :256]^T + b_ih     [256,2048]
    gemm_bt<<<dim3(32, 4), 256, 0, stream>>>(feats, W_ih, b_ih, nullptr, gin_base,
        256, 2048, 256, 256, 512, 2048, 0, 1);
    // 4. ctx_all = caps @ W_att[:, 256:]^T + att_base  [32768,256]
    gemm_bt<<<dim3(4, 512), 256, 0, stream>>>(caps, W_att + 256, nullptr, att_base, ctx_all,
        32768, 256, 512, 512, 768, 256, 256, Tt);
    // 5. gin_all = ctx_all @ W_ih[:, 256:]^T + gin_base + b_hh   [32768,2048]
    gemm_bt<<<dim3(32, 512), 256, 0, stream>>>(ctx_all, W_ih + 256, b_hh, gin_base, gin_all,
        32768, 2048, 256, 256, 512, 2048, 2048, Tt);

    // 6. recurrence: persistent kernel, 256 blocks x 1024 thr, flag-synced
    {
        void* args[] = { (void*)&gin_all, (void*)&W_hh, (void*)&hA, (void*)&hB,
                         (void*)&hiddens, (void*)&flags };
        hipLaunchCooperativeKernel((void*)lstm_seq, dim3(256), dim3(1024),
                                   args, 0, stream);
    }

    // 7. out = hiddens @ W_out^T + b_out   [32768,1004]
    gemm_bt<<<dim3(16, 512), 256, 0, stream>>>(hiddens, W_out, b_out, nullptr, out,
        32768, 1004, 512, 512, 512, 1004, 0, 1);
}